// Round 3
// baseline (883.038 us; speedup 1.0000x reference)
//
#include <hip/hip_runtime.h>
#include <math.h>

#define HID 4096
#define NH 32
#define HD 128
#define BB 8
#define SS 8
#define MM 64              // B*S rows
#define MAXT 4096
#define QKV_N (3*HID)      // 12288
#define KSPLIT 4
#define CHUNK 512
#define NCHUNK (MAXT/CHUNK)   // 8
#define TILE 32
#define NTILES (CHUNK/TILE)   // 16
#define NT 64
#define KC 32

__device__ __forceinline__ float wred_sum(float v) {
#pragma unroll
    for (int i = 1; i < 64; i <<= 1) v += __shfl_xor(v, i, 64);
    return v;
}
// half-wave (32-lane) reductions: masks 1..16 never cross the lane-32 boundary
__device__ __forceinline__ float hred_sum(float v) {
#pragma unroll
    for (int i = 1; i < 32; i <<= 1) v += __shfl_xor(v, i, 64);
    return v;
}
__device__ __forceinline__ float hred_max(float v) {
#pragma unroll
    for (int i = 1; i < 32; i <<= 1) v = fmaxf(v, __shfl_xor(v, i, 64));
    return v;
}

// -------------------- LayerNorm: 64 rows of 4096 --------------------
__global__ __launch_bounds__(256)
void ln_kernel(const float* __restrict__ tokens, const float* __restrict__ gamma,
               const float* __restrict__ beta, float* __restrict__ xout) {
    const int row = blockIdx.x;
    const float* in = tokens + (size_t)row * HID;
    float* out = xout + (size_t)row * HID;
    const int tid = threadIdx.x;
    float s = 0.f, s2 = 0.f;
    float4 vals[4];
#pragma unroll
    for (int i = 0; i < 4; ++i) {
        float4 v = *(const float4*)(in + (size_t)(i*256 + tid)*4);
        vals[i] = v;
        s  += v.x + v.y + v.z + v.w;
        s2 += v.x*v.x + v.y*v.y + v.z*v.z + v.w*v.w;
    }
    s = wred_sum(s); s2 = wred_sum(s2);
    __shared__ float red[8];
    int wid = tid >> 6, lane = tid & 63;
    if (lane == 0) { red[wid] = s; red[4+wid] = s2; }
    __syncthreads();
    s  = red[0]+red[1]+red[2]+red[3];
    s2 = red[4]+red[5]+red[6]+red[7];
    float mean = s * (1.f/HID);
    float var  = s2 * (1.f/HID) - mean*mean;
    float rstd = rsqrtf(var + 1e-5f);
#pragma unroll
    for (int i = 0; i < 4; ++i) {
        int base = (i*256 + tid)*4;
        float4 v = vals[i];
        float4 g  = *(const float4*)(gamma + base);
        float4 bt = *(const float4*)(beta + base);
        float4 o;
        o.x = (v.x - mean)*rstd*g.x + bt.x;
        o.y = (v.y - mean)*rstd*g.y + bt.y;
        o.z = (v.z - mean)*rstd*g.z + bt.z;
        o.w = (v.w - mean)*rstd*g.w + bt.w;
        *(float4*)(out + base) = o;
    }
}

// ------------- fp32 GEMM: y_part[kc][m][n] = sum_k x[m,k]*w[n,k] -------------
__global__ __launch_bounds__(256)
void gemm_part(const float* __restrict__ x, const float* __restrict__ w,
               float* __restrict__ part, int N, int K) {
    __shared__ float xt[KC][MM + 4];
    __shared__ float wt[KC][NT + 4];
    const int n0 = blockIdx.x * NT;
    const int kc = blockIdx.y;
    const int kLen = K / KSPLIT;
    const int kBeg = kc * kLen;
    const int tid = threadIdx.x;
    const int mg = tid >> 4;
    const int ng = tid & 15;
    const int lr = tid >> 2;
    const int lk = (tid & 3) * 8;
    float acc[4][4] = {{0.f}};
    const float* xsrc = x + (size_t)lr * K + kBeg + lk;
    const float* wsrc = w + (size_t)(n0 + lr) * K + kBeg + lk;
    for (int kk = 0; kk < kLen; kk += KC) {
        float4 a0 = *(const float4*)(xsrc + kk);
        float4 a1 = *(const float4*)(xsrc + kk + 4);
        float4 b0 = *(const float4*)(wsrc + kk);
        float4 b1 = *(const float4*)(wsrc + kk + 4);
        __syncthreads();
        xt[lk+0][lr]=a0.x; xt[lk+1][lr]=a0.y; xt[lk+2][lr]=a0.z; xt[lk+3][lr]=a0.w;
        xt[lk+4][lr]=a1.x; xt[lk+5][lr]=a1.y; xt[lk+6][lr]=a1.z; xt[lk+7][lr]=a1.w;
        wt[lk+0][lr]=b0.x; wt[lk+1][lr]=b0.y; wt[lk+2][lr]=b0.z; wt[lk+3][lr]=b0.w;
        wt[lk+4][lr]=b1.x; wt[lk+5][lr]=b1.y; wt[lk+6][lr]=b1.z; wt[lk+7][lr]=b1.w;
        __syncthreads();
#pragma unroll
        for (int k = 0; k < KC; ++k) {
            float4 xv = *(const float4*)&xt[k][mg*4];
            float4 wv = *(const float4*)&wt[k][ng*4];
            acc[0][0] += xv.x*wv.x; acc[0][1] += xv.x*wv.y; acc[0][2] += xv.x*wv.z; acc[0][3] += xv.x*wv.w;
            acc[1][0] += xv.y*wv.x; acc[1][1] += xv.y*wv.y; acc[1][2] += xv.y*wv.z; acc[1][3] += xv.y*wv.w;
            acc[2][0] += xv.z*wv.x; acc[2][1] += xv.z*wv.y; acc[2][2] += xv.z*wv.z; acc[2][3] += xv.z*wv.w;
            acc[3][0] += xv.w*wv.x; acc[3][1] += xv.w*wv.y; acc[3][2] += xv.w*wv.z; acc[3][3] += xv.w*wv.w;
        }
    }
    float* dst = part + (size_t)kc * MM * N + (size_t)(mg*4) * N + n0 + ng*4;
#pragma unroll
    for (int i = 0; i < 4; ++i) {
        float4 o = make_float4(acc[i][0], acc[i][1], acc[i][2], acc[i][3]);
        *(float4*)(dst + (size_t)i * N) = o;
    }
}

// ---------------- sum KSPLIT partials + bias ----------------
__global__ __launch_bounds__(256)
void combine_bias(const float* __restrict__ part, const float* __restrict__ bias,
                  float* __restrict__ out, int N, int totalv4) {
    int idx = blockIdx.x * 256 + threadIdx.x;
    if (idx >= totalv4) return;
    size_t base = (size_t)idx * 4;
    size_t MN = (size_t)MM * N;
    float4 a = *(const float4*)(part + base);
    float4 b = *(const float4*)(part + MN + base);
    float4 c = *(const float4*)(part + 2*MN + base);
    float4 d = *(const float4*)(part + 3*MN + base);
    int n = (int)(base % (size_t)N);
    float4 bb = *(const float4*)(bias + n);
    float4 o;
    o.x = a.x+b.x+c.x+d.x+bb.x;
    o.y = a.y+b.y+c.y+d.y+bb.y;
    o.z = a.z+b.z+c.z+d.z+bb.z;
    o.w = a.w+b.w+c.w+d.w+bb.w;
    *(float4*)(out + base) = o;
}

// ---------------- attention partial: one (b,h) x one T-chunk ----------------
// TILE=32 K tile in LDS (named-reg prefetch, clean XOR swizzle); V direct
// from global; per-half-wave online softmax (each half-wave owns one s row).
__global__ __launch_bounds__(256, 6)
void attn_part(const float* __restrict__ qkv, const float* __restrict__ cache_k,
               const float* __restrict__ cache_v, const int* __restrict__ d_start,
               float* __restrict__ accp, float* __restrict__ mlp) {
    __shared__ float k_lds[TILE*HD];   // 16KB
    __shared__ float q_lds[SS*HD];     // 4KB
    __shared__ float p_lds[SS*TILE];   // 1KB
    const int bh = blockIdx.x;
    const int b = bh >> 5, h = bh & 31;
    const int c = blockIdx.y;
    const int tid = threadIdx.x;
    const int start = d_start[0];
    const int T = start + SS;
    const float scale = 0.08838834764831845f;   // 1/sqrt(128)

    {   // load q tile (8 x 128)
        int s_ = tid >> 5, dg = tid & 31;
        *(float4*)&q_lds[s_*HD + dg*4] =
            *(const float4*)(qkv + (size_t)(b*SS + s_)*QKV_N + h*HD + dg*4);
    }
    const int ts  = tid & 31;          // score/staging/PV t or d index
    const int s   = tid >> 5;          // 0..7: this thread's s row (half-wave owns s)
    const int dgv = tid & 31;          // PV d-slice
    const int sr  = tid >> 3;          // staging row 0..31
    const int sq  = tid & 7;           // staging slot group

    float m_r = -1e30f, l_r = 0.f;
    float4 oacc = make_float4(0.f,0.f,0.f,0.f);
    float4 k0, k1, k2, k3;             // named regs -> no scratch spill

    const size_t cacheRowBase = ((size_t)b*MAXT*NH + h) * (size_t)HD;

#define KROW(tg) (((tg) >= start && (tg) < T) ? (qkv + (size_t)(b*SS + ((tg)-start))*QKV_N + h*HD + HID) \
                                : (cache_k + cacheRowBase + (size_t)(tg)*NH*HD))
#define VROW(tg) (((tg) >= start && (tg) < T) ? (qkv + (size_t)(b*SS + ((tg)-start))*QKV_N + h*HD + 2*HID) \
                                : (cache_v + cacheRowBase + (size_t)(tg)*NH*HD))

    {   // prefetch tile 0: lane covers row sr, slots {sq, 8+sq, 16+sq, 24+sq}
        const float* src = KROW(c*CHUNK + sr);
        k0 = *(const float4*)(src + (0*8+sq)*4);
        k1 = *(const float4*)(src + (1*8+sq)*4);
        k2 = *(const float4*)(src + (2*8+sq)*4);
        k3 = *(const float4*)(src + (3*8+sq)*4);
    }

    for (int tile = 0; tile < NTILES; ++tile) {
        const int tbase = c*CHUNK + tile*TILE;
        __syncthreads();   // previous tile's k_lds readers done
        {   // swizzled write: slot' = slot ^ (row&7)
            const int r7 = sr & 7;
            *(float4*)&k_lds[sr*HD + (((0*8+sq) ^ r7) << 2)] = k0;
            *(float4*)&k_lds[sr*HD + (((1*8+sq) ^ r7) << 2)] = k1;
            *(float4*)&k_lds[sr*HD + (((2*8+sq) ^ r7) << 2)] = k2;
            *(float4*)&k_lds[sr*HD + (((3*8+sq) ^ r7) << 2)] = k3;
        }
        __syncthreads();   // k_lds ready
        if (tile + 1 < NTILES) {   // prefetch next tile; latency hides under compute
            const float* src = KROW(tbase + TILE + sr);
            k0 = *(const float4*)(src + (0*8+sq)*4);
            k1 = *(const float4*)(src + (1*8+sq)*4);
            k2 = *(const float4*)(src + (2*8+sq)*4);
            k3 = *(const float4*)(src + (3*8+sq)*4);
        }
        // ---- score: lane computes dot(q[s], K[ts]) ----
        float d0 = 0.f;
        const float* qrow = q_lds + s*HD;
        const int t7 = ts & 7;
#pragma unroll
        for (int dg = 0; dg < 32; ++dg) {
            float4 kv = *(const float4*)&k_lds[ts*HD + ((dg ^ t7) << 2)];
            float4 qa = *(const float4*)(qrow + dg*4);
            d0 += kv.x*qa.x + kv.y*qa.y + kv.z*qa.z + kv.w*qa.w;
        }
        int tg = tbase + ts;
        float sc = (tg < T) ? d0 * scale : -1e30f;
        // ---- online softmax per half-wave (one s per half) ----
        float mt = hred_max(sc);
        float mn = fmaxf(m_r, mt);
        float al = __expf(m_r - mn);
        float p  = (tg < T) ? __expf(sc - mn) : 0.f;
        l_r = l_r * al + hred_sum(p);
        m_r = mn;
        p_lds[s*TILE + ts] = p;   // written & read only by this half-wave
        // ---- PV: V direct from global ----
        oacc.x *= al; oacc.y *= al; oacc.z *= al; oacc.w *= al;
        if (tbase + TILE <= start) {   // hot path: pure cache, affine addresses
            const float* vb = cache_v + cacheRowBase + (size_t)tbase*NH*HD + dgv*4;
#pragma unroll
            for (int t2 = 0; t2 < TILE; ++t2) {
                float4 vv = *(const float4*)(vb + (size_t)t2*NH*HD);
                float pp = p_lds[s*TILE + t2];
                oacc.x += pp*vv.x; oacc.y += pp*vv.y; oacc.z += pp*vv.z; oacc.w += pp*vv.w;
            }
        } else {                        // tail: mixed qkv/cache sources
#pragma unroll 8
            for (int t2 = 0; t2 < TILE; ++t2) {
                int tg2 = tbase + t2;
                const float* vrow = VROW(tg2);
                float4 vv = *(const float4*)(vrow + dgv*4);
                float pp = p_lds[s*TILE + t2];   // p==0 for invalid rows
                oacc.x += pp*vv.x; oacc.y += pp*vv.y; oacc.z += pp*vv.z; oacc.w += pp*vv.w;
            }
        }
    }
    size_t pbase = ((size_t)(bh*NCHUNK + c) * SS + s) * HD + dgv*4;
    *(float4*)(accp + pbase) = oacc;
    if ((tid & 31) == 0) {
        size_t mb = (size_t)(bh*NCHUNK + c) * 16;
        mlp[mb + s] = m_r;
        mlp[mb + 8 + s] = l_r;
    }
#undef KROW
#undef VROW
}

// ---------------- combine chunk partials -> attn_out (64 x 4096) ----------------
__global__ __launch_bounds__(256)
void attn_combine(const float* __restrict__ accp, const float* __restrict__ mlp,
                  float* __restrict__ attn_out) {
    const int bh = blockIdx.x;
    const int b = bh >> 5, h = bh & 31;
    const int tid = threadIdx.x;
    const int s = tid >> 5, dg = tid & 31;
    float mC[NCHUNK], lC[NCHUNK];
    float M = -1e30f;
#pragma unroll
    for (int c = 0; c < NCHUNK; ++c) {
        size_t mb = (size_t)(bh*NCHUNK + c) * 16;
        mC[c] = mlp[mb + s];
        lC[c] = mlp[mb + 8 + s];
        M = fmaxf(M, mC[c]);
    }
    float L = 0.f;
    float4 o = make_float4(0.f,0.f,0.f,0.f);
#pragma unroll
    for (int c = 0; c < NCHUNK; ++c) {
        float wgt = __expf(mC[c] - M);
        L += wgt * lC[c];
        float4 a = *(const float4*)(accp + ((size_t)(bh*NCHUNK + c) * SS + s) * HD + dg*4);
        o.x += wgt*a.x; o.y += wgt*a.y; o.z += wgt*a.z; o.w += wgt*a.w;
    }
    float inv = 1.f / L;
    o.x *= inv; o.y *= inv; o.z *= inv; o.w *= inv;
    *(float4*)(attn_out + (size_t)(b*SS + s)*HID + h*HD + dg*4) = o;
}

extern "C" void kernel_launch(void* const* d_in, const int* in_sizes, int n_in,
                              void* d_out, int out_size, void* d_ws, size_t ws_size,
                              hipStream_t stream) {
    const float* tokens  = (const float*)d_in[0];
    const float* cache_k = (const float*)d_in[1];
    const float* cache_v = (const float*)d_in[2];
    const float* gamma   = (const float*)d_in[3];
    const float* beta    = (const float*)d_in[4];
    const float* qkv_w   = (const float*)d_in[5];
    const float* qkv_b   = (const float*)d_in[6];
    const float* proj_w  = (const float*)d_in[7];
    const float* proj_b  = (const float*)d_in[8];
    const int*   d_start = (const int*)d_in[9];
    float* out = (float*)d_out;
    char* ws = (char*)d_ws;

    // layout: x_ln [0,1M) | qkv [1M,4M) | part/accp [4M,16M) | mlp [12M,12.25M)
    // accp [4M,12M) is reused by proj partials [4M,8M) only AFTER attn_combine.
    float* x_ln     = (float*)ws;
    float* qkv      = (float*)(ws + (1u<<20));
    float* part     = (float*)(ws + (4u<<20));
    float* accp     = (float*)(ws + (4u<<20));
    float* mlp      = (float*)(ws + (12u<<20));
    float* attn_out = (float*)(ws + (16u<<20));

    ln_kernel<<<MM, 256, 0, stream>>>(tokens, gamma, beta, x_ln);
    gemm_part<<<dim3(QKV_N/NT, KSPLIT), 256, 0, stream>>>(x_ln, qkv_w, part, QKV_N, HID);
    combine_bias<<<(MM*QKV_N/4 + 255)/256, 256, 0, stream>>>(part, qkv_b, qkv, QKV_N, MM*QKV_N/4);
    attn_part<<<dim3(BB*NH, NCHUNK), 256, 0, stream>>>(qkv, cache_k, cache_v, d_start, accp, mlp);
    attn_combine<<<BB*NH, 256, 0, stream>>>(accp, mlp, attn_out);
    gemm_part<<<dim3(HID/NT, KSPLIT), 256, 0, stream>>>(attn_out, proj_w, part, HID, HID);
    combine_bias<<<(MM*HID/4 + 255)/256, 256, 0, stream>>>(part, proj_b, out, HID, MM*HID/4);
}

// Round 4
// 426.863 us; speedup vs baseline: 2.0687x; 2.0687x over previous
//
#include <hip/hip_runtime.h>
#include <math.h>

#define HID 4096
#define NH 32
#define HD 128
#define BB 8
#define SS 8
#define MM 64              // B*S rows
#define MAXT 4096
#define QKV_N (3*HID)      // 12288
#define KSPLIT 4
#define CHUNK 1024
#define NCHUNK (MAXT/CHUNK)   // 4
#define TILE 32
#define NTILES (CHUNK/TILE)   // 32
#define CHUNK_STRIDE 260      // floats per 2-row K chunk (1040 B: +16B pad rotates bank quad)
#define KBUF_FLOATS (16*CHUNK_STRIDE)   // 4160 floats per tile buffer
#define NT 64
#define KC 32

__device__ __forceinline__ float wred_sum(float v) {
#pragma unroll
    for (int i = 1; i < 64; i <<= 1) v += __shfl_xor(v, i, 64);
    return v;
}
// half-wave (32-lane) reductions
__device__ __forceinline__ float hred_sum(float v) {
#pragma unroll
    for (int i = 1; i < 32; i <<= 1) v += __shfl_xor(v, i, 64);
    return v;
}
__device__ __forceinline__ float hred_max(float v) {
#pragma unroll
    for (int i = 1; i < 32; i <<= 1) v = fmaxf(v, __shfl_xor(v, i, 64));
    return v;
}

// -------------------- LayerNorm: 64 rows of 4096 --------------------
__global__ __launch_bounds__(256)
void ln_kernel(const float* __restrict__ tokens, const float* __restrict__ gamma,
               const float* __restrict__ beta, float* __restrict__ xout) {
    const int row = blockIdx.x;
    const float* in = tokens + (size_t)row * HID;
    float* out = xout + (size_t)row * HID;
    const int tid = threadIdx.x;
    float s = 0.f, s2 = 0.f;
    float4 vals[4];
#pragma unroll
    for (int i = 0; i < 4; ++i) {
        float4 v = *(const float4*)(in + (size_t)(i*256 + tid)*4);
        vals[i] = v;
        s  += v.x + v.y + v.z + v.w;
        s2 += v.x*v.x + v.y*v.y + v.z*v.z + v.w*v.w;
    }
    s = wred_sum(s); s2 = wred_sum(s2);
    __shared__ float red[8];
    int wid = tid >> 6, lane = tid & 63;
    if (lane == 0) { red[wid] = s; red[4+wid] = s2; }
    __syncthreads();
    s  = red[0]+red[1]+red[2]+red[3];
    s2 = red[4]+red[5]+red[6]+red[7];
    float mean = s * (1.f/HID);
    float var  = s2 * (1.f/HID) - mean*mean;
    float rstd = rsqrtf(var + 1e-5f);
#pragma unroll
    for (int i = 0; i < 4; ++i) {
        int base = (i*256 + tid)*4;
        float4 v = vals[i];
        float4 g  = *(const float4*)(gamma + base);
        float4 bt = *(const float4*)(beta + base);
        float4 o;
        o.x = (v.x - mean)*rstd*g.x + bt.x;
        o.y = (v.y - mean)*rstd*g.y + bt.y;
        o.z = (v.z - mean)*rstd*g.z + bt.z;
        o.w = (v.w - mean)*rstd*g.w + bt.w;
        *(float4*)(out + base) = o;
    }
}

// ------------- fp32 GEMM: y_part[kc][m][n] = sum_k x[m,k]*w[n,k] -------------
__global__ __launch_bounds__(256)
void gemm_part(const float* __restrict__ x, const float* __restrict__ w,
               float* __restrict__ part, int N, int K) {
    __shared__ float xt[KC][MM + 4];
    __shared__ float wt[KC][NT + 4];
    const int n0 = blockIdx.x * NT;
    const int kc = blockIdx.y;
    const int kLen = K / KSPLIT;
    const int kBeg = kc * kLen;
    const int tid = threadIdx.x;
    const int mg = tid >> 4;
    const int ng = tid & 15;
    const int lr = tid >> 2;
    const int lk = (tid & 3) * 8;
    float acc[4][4] = {{0.f}};
    const float* xsrc = x + (size_t)lr * K + kBeg + lk;
    const float* wsrc = w + (size_t)(n0 + lr) * K + kBeg + lk;
    for (int kk = 0; kk < kLen; kk += KC) {
        float4 a0 = *(const float4*)(xsrc + kk);
        float4 a1 = *(const float4*)(xsrc + kk + 4);
        float4 b0 = *(const float4*)(wsrc + kk);
        float4 b1 = *(const float4*)(wsrc + kk + 4);
        __syncthreads();
        xt[lk+0][lr]=a0.x; xt[lk+1][lr]=a0.y; xt[lk+2][lr]=a0.z; xt[lk+3][lr]=a0.w;
        xt[lk+4][lr]=a1.x; xt[lk+5][lr]=a1.y; xt[lk+6][lr]=a1.z; xt[lk+7][lr]=a1.w;
        wt[lk+0][lr]=b0.x; wt[lk+1][lr]=b0.y; wt[lk+2][lr]=b0.z; wt[lk+3][lr]=b0.w;
        wt[lk+4][lr]=b1.x; wt[lk+5][lr]=b1.y; wt[lk+6][lr]=b1.z; wt[lk+7][lr]=b1.w;
        __syncthreads();
#pragma unroll
        for (int k = 0; k < KC; ++k) {
            float4 xv = *(const float4*)&xt[k][mg*4];
            float4 wv = *(const float4*)&wt[k][ng*4];
            acc[0][0] += xv.x*wv.x; acc[0][1] += xv.x*wv.y; acc[0][2] += xv.x*wv.z; acc[0][3] += xv.x*wv.w;
            acc[1][0] += xv.y*wv.x; acc[1][1] += xv.y*wv.y; acc[1][2] += xv.y*wv.z; acc[1][3] += xv.y*wv.w;
            acc[2][0] += xv.z*wv.x; acc[2][1] += xv.z*wv.y; acc[2][2] += xv.z*wv.z; acc[2][3] += xv.z*wv.w;
            acc[3][0] += xv.w*wv.x; acc[3][1] += xv.w*wv.y; acc[3][2] += xv.w*wv.z; acc[3][3] += xv.w*wv.w;
        }
    }
    float* dst = part + (size_t)kc * MM * N + (size_t)(mg*4) * N + n0 + ng*4;
#pragma unroll
    for (int i = 0; i < 4; ++i) {
        float4 o = make_float4(acc[i][0], acc[i][1], acc[i][2], acc[i][3]);
        *(float4*)(dst + (size_t)i * N) = o;
    }
}

// ---------------- sum KSPLIT partials + bias ----------------
__global__ __launch_bounds__(256)
void combine_bias(const float* __restrict__ part, const float* __restrict__ bias,
                  float* __restrict__ out, int N, int totalv4) {
    int idx = blockIdx.x * 256 + threadIdx.x;
    if (idx >= totalv4) return;
    size_t base = (size_t)idx * 4;
    size_t MN = (size_t)MM * N;
    float4 a = *(const float4*)(part + base);
    float4 b = *(const float4*)(part + MN + base);
    float4 c = *(const float4*)(part + 2*MN + base);
    float4 d = *(const float4*)(part + 3*MN + base);
    int n = (int)(base % (size_t)N);
    float4 bb = *(const float4*)(bias + n);
    float4 o;
    o.x = a.x+b.x+c.x+d.x+bb.x;
    o.y = a.y+b.y+c.y+d.y+bb.y;
    o.z = a.z+b.z+c.z+d.z+bb.z;
    o.w = a.w+b.w+c.w+d.w+bb.w;
    *(float4*)(out + base) = o;
}

// ---------------- attention partial: one (b,h) x one T-chunk ----------------
// K staged via global_load_lds DMA (double-buffered, padded-chunk layout:
// chunk = 2 rows = 1KB at 1040B stride -> score reads are 2-way max = free).
// V direct from global (broadcast across half-waves). One barrier per tile.
__global__ __launch_bounds__(256, 4)
void attn_part(const float* __restrict__ qkv, const float* __restrict__ cache_k,
               const float* __restrict__ cache_v, const int* __restrict__ d_start,
               float* __restrict__ accp, float* __restrict__ mlp) {
    __shared__ float k_lds[2*KBUF_FLOATS];   // 33280 B
    __shared__ float q_lds[SS*HD];           // 4 KB
    __shared__ float p_lds[SS*TILE];         // 1 KB
    const int bh = blockIdx.x;
    const int b = bh >> 5, h = bh & 31;
    const int c = blockIdx.y;
    const int tid = threadIdx.x;
    const int start = d_start[0];
    const int T = start + SS;
    const float scale = 0.08838834764831845f;   // 1/sqrt(128)

    {   // load q tile (8 x 128)
        int s_ = tid >> 5, dg = tid & 31;
        *(float4*)&q_lds[s_*HD + dg*4] =
            *(const float4*)(qkv + (size_t)(b*SS + s_)*QKV_N + h*HD + dg*4);
    }
    const int ts   = tid & 31;         // score t index / PV d-slice
    const int s    = tid >> 5;         // 0..7: half-wave owns s row
    const int wave = tid >> 6;
    const int lane = tid & 63;
    const int hi   = lane >> 5;        // row within 2-row chunk
    const int li   = lane & 31;        // 16B slot within row

    const size_t cacheRowBase = ((size_t)b*MAXT*NH + h) * (size_t)HD;

    // DMA-stage one K tile (32 rows) into buffer `buf`; wave handles 4 chunks.
    auto stage_tile = [&](int tbase, int buf) {
        float* base = k_lds + buf*KBUF_FLOATS;
#pragma unroll
        for (int j = 0; j < 4; ++j) {
            int ck = wave*4 + j;
            int tg = tbase + 2*ck + hi;
            const float* src = ((tg >= start && tg < T)
                ? (qkv + (size_t)(b*SS + (tg-start))*QKV_N + h*HD + HID)
                : (cache_k + cacheRowBase + (size_t)tg*NH*HD)) + li*4;
            __builtin_amdgcn_global_load_lds(
                (const __attribute__((address_space(1))) void*)src,
                (__attribute__((address_space(3))) void*)(base + ck*CHUNK_STRIDE),
                16, 0, 0);
        }
    };

    float m_r = -1e30f, l_r = 0.f;
    float4 oacc = make_float4(0.f,0.f,0.f,0.f);
    const int cbase = c*CHUNK;

    stage_tile(cbase, 0);
    asm volatile("s_waitcnt vmcnt(0)" ::: "memory");
    __syncthreads();

    int buf = 0;
    for (int tile = 0; tile < NTILES; ++tile) {
        const int tbase = cbase + tile*TILE;
        if (tile + 1 < NTILES) stage_tile(tbase + TILE, buf ^ 1);   // async into nxt

        // ---- score: lane computes dot(q[s], K[ts]) from padded-chunk layout ----
        const float* kb = k_lds + buf*KBUF_FLOATS + (ts>>1)*CHUNK_STRIDE + (ts&1)*HD;
        const float* qrow = q_lds + s*HD;
        float d0 = 0.f;
#pragma unroll
        for (int dg = 0; dg < 32; ++dg) {
            float4 kv = *(const float4*)(kb + dg*4);
            float4 qa = *(const float4*)(qrow + dg*4);
            d0 += kv.x*qa.x + kv.y*qa.y + kv.z*qa.z + kv.w*qa.w;
        }
        int tg = tbase + ts;
        float sc = (tg < T) ? d0 * scale : -1e30f;
        // ---- online softmax per half-wave ----
        float mt = hred_max(sc);
        float mn = fmaxf(m_r, mt);
        float al = __expf(m_r - mn);
        float p  = (tg < T) ? __expf(sc - mn) : 0.f;
        l_r = l_r * al + hred_sum(p);
        m_r = mn;
        p_lds[s*TILE + ts] = p;   // intra-half-wave only
        // ---- PV: V direct from global ----
        oacc.x *= al; oacc.y *= al; oacc.z *= al; oacc.w *= al;
        if (tbase + TILE <= start) {   // pure-cache hot path: affine addresses
            const float* vb = cache_v + cacheRowBase + (size_t)tbase*NH*HD + ts*4;
#pragma unroll 16
            for (int t2 = 0; t2 < TILE; ++t2) {
                float4 vv = *(const float4*)(vb + (size_t)t2*NH*HD);
                float pp = p_lds[s*TILE + t2];
                oacc.x += pp*vv.x; oacc.y += pp*vv.y; oacc.z += pp*vv.z; oacc.w += pp*vv.w;
            }
        } else {                        // tail: mixed qkv/cache sources
#pragma unroll 8
            for (int t2 = 0; t2 < TILE; ++t2) {
                int tg2 = tbase + t2;
                const float* vrow = ((tg2 >= start && tg2 < T)
                    ? (qkv + (size_t)(b*SS + (tg2-start))*QKV_N + h*HD + 2*HID)
                    : (cache_v + cacheRowBase + (size_t)tg2*NH*HD));
                float4 vv = *(const float4*)(vrow + ts*4);
                float pp = p_lds[s*TILE + t2];   // p==0 for invalid rows
                oacc.x += pp*vv.x; oacc.y += pp*vv.y; oacc.z += pp*vv.z; oacc.w += pp*vv.w;
            }
        }
        asm volatile("s_waitcnt vmcnt(0)" ::: "memory");   // nxt K arrived
        __syncthreads();
        buf ^= 1;
    }

    size_t pbase = ((size_t)(bh*NCHUNK + c) * SS + s) * HD + ts*4;
    *(float4*)(accp + pbase) = oacc;
    if (ts == 0) {
        size_t mb = (size_t)(bh*NCHUNK + c) * 16;
        mlp[mb + s] = m_r;
        mlp[mb + 8 + s] = l_r;
    }
}

// ---------------- combine chunk partials -> attn_out (64 x 4096) ----------------
__global__ __launch_bounds__(256)
void attn_combine(const float* __restrict__ accp, const float* __restrict__ mlp,
                  float* __restrict__ attn_out) {
    const int bh = blockIdx.x;
    const int b = bh >> 5, h = bh & 31;
    const int tid = threadIdx.x;
    const int s = tid >> 5, dg = tid & 31;
    float mC[NCHUNK], lC[NCHUNK];
    float M = -1e30f;
#pragma unroll
    for (int c = 0; c < NCHUNK; ++c) {
        size_t mb = (size_t)(bh*NCHUNK + c) * 16;
        mC[c] = mlp[mb + s];
        lC[c] = mlp[mb + 8 + s];
        M = fmaxf(M, mC[c]);
    }
    float L = 0.f;
    float4 o = make_float4(0.f,0.f,0.f,0.f);
#pragma unroll
    for (int c = 0; c < NCHUNK; ++c) {
        float wgt = __expf(mC[c] - M);
        L += wgt * lC[c];
        float4 a = *(const float4*)(accp + ((size_t)(bh*NCHUNK + c) * SS + s) * HD + dg*4);
        o.x += wgt*a.x; o.y += wgt*a.y; o.z += wgt*a.z; o.w += wgt*a.w;
    }
    float inv = 1.f / L;
    o.x *= inv; o.y *= inv; o.z *= inv; o.w *= inv;
    *(float4*)(attn_out + (size_t)(b*SS + s)*HID + h*HD + dg*4) = o;
}

extern "C" void kernel_launch(void* const* d_in, const int* in_sizes, int n_in,
                              void* d_out, int out_size, void* d_ws, size_t ws_size,
                              hipStream_t stream) {
    const float* tokens  = (const float*)d_in[0];
    const float* cache_k = (const float*)d_in[1];
    const float* cache_v = (const float*)d_in[2];
    const float* gamma   = (const float*)d_in[3];
    const float* beta    = (const float*)d_in[4];
    const float* qkv_w   = (const float*)d_in[5];
    const float* qkv_b   = (const float*)d_in[6];
    const float* proj_w  = (const float*)d_in[7];
    const float* proj_b  = (const float*)d_in[8];
    const int*   d_start = (const int*)d_in[9];
    float* out = (float*)d_out;
    char* ws = (char*)d_ws;

    // layout: x_ln [0,1M) | qkv [1M,4M) | part/accp [4M,16M) | mlp [12M,12.25M)
    // (mlp overlaps qkv-gemm partial region but is written only after combine;
    //  proj partials use only [4M,8M), after attn_combine has consumed accp.)
    float* x_ln     = (float*)ws;
    float* qkv      = (float*)(ws + (1u<<20));
    float* part     = (float*)(ws + (4u<<20));
    float* accp     = (float*)(ws + (4u<<20));
    float* mlp      = (float*)(ws + (12u<<20));
    float* attn_out = (float*)(ws + (16u<<20));

    ln_kernel<<<MM, 256, 0, stream>>>(tokens, gamma, beta, x_ln);
    gemm_part<<<dim3(QKV_N/NT, KSPLIT), 256, 0, stream>>>(x_ln, qkv_w, part, QKV_N, HID);
    combine_bias<<<(MM*QKV_N/4 + 255)/256, 256, 0, stream>>>(part, qkv_b, qkv, QKV_N, MM*QKV_N/4);
    attn_part<<<dim3(BB*NH, NCHUNK), 256, 0, stream>>>(qkv, cache_k, cache_v, d_start, accp, mlp);
    attn_combine<<<BB*NH, 256, 0, stream>>>(accp, mlp, attn_out);
    gemm_part<<<dim3(HID/NT, KSPLIT), 256, 0, stream>>>(attn_out, proj_w, part, HID, HID);
    combine_bias<<<(MM*HID/4 + 255)/256, 256, 0, stream>>>(part, proj_b, out, HID, MM*HID/4);
}

// Round 5
// 345.065 us; speedup vs baseline: 2.5591x; 1.2371x over previous
//
#include <hip/hip_runtime.h>
#include <math.h>

#define HID 4096
#define NH 32
#define HD 128
#define BB 8
#define SS 8
#define MM 64              // B*S rows
#define MAXT 4096
#define QKV_N (3*HID)      // 12288
#define KSPLIT 4
#define CHUNK 1024
#define NCHUNK (MAXT/CHUNK)   // 4
#define TILE 32
#define NTILES (CHUNK/TILE)   // 32
#define CHUNK_STRIDE 260      // floats per 2-row K chunk (1040 B pad rotates bank quad)
#define KBUF_FLOATS (16*CHUNK_STRIDE)
#define GBK 64                // GEMM K-step
#define ASTR 72               // LDS row stride in bf16 (64 + 8 pad -> uniform banks)

typedef __attribute__((ext_vector_type(8))) __bf16 bf16x8;
typedef __attribute__((ext_vector_type(4))) float f32x4;

__device__ __forceinline__ float wred_sum(float v) {
#pragma unroll
    for (int i = 1; i < 64; i <<= 1) v += __shfl_xor(v, i, 64);
    return v;
}
__device__ __forceinline__ float hred_sum(float v) {
#pragma unroll
    for (int i = 1; i < 32; i <<= 1) v += __shfl_xor(v, i, 64);
    return v;
}
__device__ __forceinline__ float hred_max(float v) {
#pragma unroll
    for (int i = 1; i < 32; i <<= 1) v = fmaxf(v, __shfl_xor(v, i, 64));
    return v;
}

// -------------------- LayerNorm: 64 rows of 4096 --------------------
__global__ __launch_bounds__(256)
void ln_kernel(const float* __restrict__ tokens, const float* __restrict__ gamma,
               const float* __restrict__ beta, float* __restrict__ xout) {
    const int row = blockIdx.x;
    const float* in = tokens + (size_t)row * HID;
    float* out = xout + (size_t)row * HID;
    const int tid = threadIdx.x;
    float s = 0.f, s2 = 0.f;
    float4 vals[4];
#pragma unroll
    for (int i = 0; i < 4; ++i) {
        float4 v = *(const float4*)(in + (size_t)(i*256 + tid)*4);
        vals[i] = v;
        s  += v.x + v.y + v.z + v.w;
        s2 += v.x*v.x + v.y*v.y + v.z*v.z + v.w*v.w;
    }
    s = wred_sum(s); s2 = wred_sum(s2);
    __shared__ float red[8];
    int wid = tid >> 6, lane = tid & 63;
    if (lane == 0) { red[wid] = s; red[4+wid] = s2; }
    __syncthreads();
    s  = red[0]+red[1]+red[2]+red[3];
    s2 = red[4]+red[5]+red[6]+red[7];
    float mean = s * (1.f/HID);
    float var  = s2 * (1.f/HID) - mean*mean;
    float rstd = rsqrtf(var + 1e-5f);
#pragma unroll
    for (int i = 0; i < 4; ++i) {
        int base = (i*256 + tid)*4;
        float4 v = vals[i];
        float4 g  = *(const float4*)(gamma + base);
        float4 bt = *(const float4*)(beta + base);
        float4 o;
        o.x = (v.x - mean)*rstd*g.x + bt.x;
        o.y = (v.y - mean)*rstd*g.y + bt.y;
        o.z = (v.z - mean)*rstd*g.z + bt.z;
        o.w = (v.w - mean)*rstd*g.w + bt.w;
        *(float4*)(out + base) = o;
    }
}

// ---------- split-bf16 MFMA GEMM: part[kc][m][n] = sum_k x[m,k]*w[n,k] ----------
// x: 64 x K fp32, w: N x K fp32. In-register bf16 hi/lo split (err ~2^-18).
// Block tile 64x64, 4 waves 2x2, each wave 2x2 of 16x16x32 MFMA tiles.
__global__ __launch_bounds__(256, 2)
void gemm_mfma(const float* __restrict__ x, const float* __restrict__ w,
               float* __restrict__ part, int N, int K) {
    __shared__ __bf16 a_hi[64*ASTR], a_lo[64*ASTR];   // 9216 B each
    __shared__ __bf16 b_hi[64*ASTR], b_lo[64*ASTR];   // total 36 KB
    const int n0 = blockIdx.x * 64;
    const int kc = blockIdx.y;
    const int kLen = K / KSPLIT;
    const int kBeg = kc * kLen;
    const int tid = threadIdx.x;
    const int wv = tid >> 6;
    const int lane = tid & 63;
    const int wm = (wv & 1) * 32;      // wave m offset
    const int wn = (wv >> 1) * 32;     // wave n offset
    const int sr = tid >> 2;           // staging row 0..63
    const int sk = (tid & 3) * 16;     // staging k offset
    const int fm = lane & 15;          // frag row
    const int fk = (lane >> 4) * 8;    // frag k offset (8 contiguous)

    f32x4 acc[2][2] = {};
    const float* xsrc = x + (size_t)sr * K + kBeg + sk;
    const float* wsrc = w + (size_t)(n0 + sr) * K + kBeg + sk;

    float aRg[16], bRg[16];
#pragma unroll
    for (int q = 0; q < 4; ++q) {
        *(float4*)&aRg[q*4] = *(const float4*)(xsrc + q*4);
        *(float4*)&bRg[q*4] = *(const float4*)(wsrc + q*4);
    }
    const int nsteps = kLen / GBK;
    for (int st = 0; st < nsteps; ++st) {
        __syncthreads();   // prev step's frag readers done
        // convert + write hi/lo to LDS
#pragma unroll
        for (int q = 0; q < 2; ++q) {
            bf16x8 ah, al, bh, bl;
#pragma unroll
            for (int j = 0; j < 8; ++j) {
                float av = aRg[q*8+j];
                __bf16 h = (__bf16)av;
                ah[j] = h;
                al[j] = (__bf16)(av - (float)h);
                float bv = bRg[q*8+j];
                __bf16 g = (__bf16)bv;
                bh[j] = g;
                bl[j] = (__bf16)(bv - (float)g);
            }
            int base = sr*ASTR + sk + q*8;
            *(bf16x8*)&a_hi[base] = ah;
            *(bf16x8*)&a_lo[base] = al;
            *(bf16x8*)&b_hi[base] = bh;
            *(bf16x8*)&b_lo[base] = bl;
        }
        __syncthreads();   // tile ready
        if (st + 1 < nsteps) {   // T14: issue next loads early, land during MFMA
            const float* xn = xsrc + (size_t)(st+1)*GBK;
            const float* wn_ = wsrc + (size_t)(st+1)*GBK;
#pragma unroll
            for (int q = 0; q < 4; ++q) {
                *(float4*)&aRg[q*4] = *(const float4*)(xn + q*4);
                *(float4*)&bRg[q*4] = *(const float4*)(wn_ + q*4);
            }
        }
#pragma unroll
        for (int kh = 0; kh < 2; ++kh) {
            bf16x8 Ah[2], Al[2], Bh[2], Bl[2];
#pragma unroll
            for (int t = 0; t < 2; ++t) {
                int ar = (wm + t*16 + fm)*ASTR + kh*32 + fk;
                Ah[t] = *(const bf16x8*)&a_hi[ar];
                Al[t] = *(const bf16x8*)&a_lo[ar];
                int br = (wn + t*16 + fm)*ASTR + kh*32 + fk;
                Bh[t] = *(const bf16x8*)&b_hi[br];
                Bl[t] = *(const bf16x8*)&b_lo[br];
            }
#pragma unroll
            for (int mt = 0; mt < 2; ++mt)
#pragma unroll
            for (int nt = 0; nt < 2; ++nt) {
                acc[mt][nt] = __builtin_amdgcn_mfma_f32_16x16x32_bf16(Ah[mt], Bh[nt], acc[mt][nt], 0, 0, 0);
                acc[mt][nt] = __builtin_amdgcn_mfma_f32_16x16x32_bf16(Ah[mt], Bl[nt], acc[mt][nt], 0, 0, 0);
                acc[mt][nt] = __builtin_amdgcn_mfma_f32_16x16x32_bf16(Al[mt], Bh[nt], acc[mt][nt], 0, 0, 0);
            }
        }
    }
    // epilogue: D row=(lane>>4)*4+reg, col=lane&15  [m89-verified mapping]
    float* dst = part + (size_t)kc * MM * N;
#pragma unroll
    for (int mt = 0; mt < 2; ++mt)
#pragma unroll
    for (int nt = 0; nt < 2; ++nt) {
        int m = wm + mt*16 + (lane >> 4)*4;
        int n = n0 + wn + nt*16 + (lane & 15);
#pragma unroll
        for (int r = 0; r < 4; ++r)
            dst[(size_t)(m + r) * N + n] = acc[mt][nt][r];
    }
}

// ---------------- sum KSPLIT partials + bias ----------------
__global__ __launch_bounds__(256)
void combine_bias(const float* __restrict__ part, const float* __restrict__ bias,
                  float* __restrict__ out, int N, int totalv4) {
    int idx = blockIdx.x * 256 + threadIdx.x;
    if (idx >= totalv4) return;
    size_t base = (size_t)idx * 4;
    size_t MN = (size_t)MM * N;
    float4 a = *(const float4*)(part + base);
    float4 b = *(const float4*)(part + MN + base);
    float4 c = *(const float4*)(part + 2*MN + base);
    float4 d = *(const float4*)(part + 3*MN + base);
    int n = (int)(base % (size_t)N);
    float4 bb = *(const float4*)(bias + n);
    float4 o;
    o.x = a.x+b.x+c.x+d.x+bb.x;
    o.y = a.y+b.y+c.y+d.y+bb.y;
    o.z = a.z+b.z+c.z+d.z+bb.z;
    o.w = a.w+b.w+c.w+d.w+bb.w;
    *(float4*)(out + base) = o;
}

// ---------------- attention partial (unchanged from round 4) ----------------
__global__ __launch_bounds__(256, 4)
void attn_part(const float* __restrict__ qkv, const float* __restrict__ cache_k,
               const float* __restrict__ cache_v, const int* __restrict__ d_start,
               float* __restrict__ accp, float* __restrict__ mlp) {
    __shared__ float k_lds[2*KBUF_FLOATS];   // 33280 B
    __shared__ float q_lds[SS*HD];           // 4 KB
    __shared__ float p_lds[SS*TILE];         // 1 KB
    const int bh = blockIdx.x;
    const int b = bh >> 5, h = bh & 31;
    const int c = blockIdx.y;
    const int tid = threadIdx.x;
    const int start = d_start[0];
    const int T = start + SS;
    const float scale = 0.08838834764831845f;   // 1/sqrt(128)

    {   // load q tile (8 x 128)
        int s_ = tid >> 5, dg = tid & 31;
        *(float4*)&q_lds[s_*HD + dg*4] =
            *(const float4*)(qkv + (size_t)(b*SS + s_)*QKV_N + h*HD + dg*4);
    }
    const int ts   = tid & 31;
    const int s    = tid >> 5;
    const int wave = tid >> 6;
    const int lane = tid & 63;
    const int hi   = lane >> 5;
    const int li   = lane & 31;

    const size_t cacheRowBase = ((size_t)b*MAXT*NH + h) * (size_t)HD;

    auto stage_tile = [&](int tbase, int buf) {
        float* base = k_lds + buf*KBUF_FLOATS;
#pragma unroll
        for (int j = 0; j < 4; ++j) {
            int ck = wave*4 + j;
            int tg = tbase + 2*ck + hi;
            const float* src = ((tg >= start && tg < T)
                ? (qkv + (size_t)(b*SS + (tg-start))*QKV_N + h*HD + HID)
                : (cache_k + cacheRowBase + (size_t)tg*NH*HD)) + li*4;
            __builtin_amdgcn_global_load_lds(
                (const __attribute__((address_space(1))) void*)src,
                (__attribute__((address_space(3))) void*)(base + ck*CHUNK_STRIDE),
                16, 0, 0);
        }
    };

    float m_r = -1e30f, l_r = 0.f;
    float4 oacc = make_float4(0.f,0.f,0.f,0.f);
    const int cbase = c*CHUNK;

    stage_tile(cbase, 0);
    asm volatile("s_waitcnt vmcnt(0)" ::: "memory");
    __syncthreads();

    int buf = 0;
    for (int tile = 0; tile < NTILES; ++tile) {
        const int tbase = cbase + tile*TILE;
        if (tile + 1 < NTILES) stage_tile(tbase + TILE, buf ^ 1);

        const float* kb = k_lds + buf*KBUF_FLOATS + (ts>>1)*CHUNK_STRIDE + (ts&1)*HD;
        const float* qrow = q_lds + s*HD;
        float d0 = 0.f;
#pragma unroll
        for (int dg = 0; dg < 32; ++dg) {
            float4 kv = *(const float4*)(kb + dg*4);
            float4 qa = *(const float4*)(qrow + dg*4);
            d0 += kv.x*qa.x + kv.y*qa.y + kv.z*qa.z + kv.w*qa.w;
        }
        int tg = tbase + ts;
        float sc = (tg < T) ? d0 * scale : -1e30f;
        float mt = hred_max(sc);
        float mn = fmaxf(m_r, mt);
        float al = __expf(m_r - mn);
        float p  = (tg < T) ? __expf(sc - mn) : 0.f;
        l_r = l_r * al + hred_sum(p);
        m_r = mn;
        p_lds[s*TILE + ts] = p;
        oacc.x *= al; oacc.y *= al; oacc.z *= al; oacc.w *= al;
        if (tbase + TILE <= start) {
            const float* vb = cache_v + cacheRowBase + (size_t)tbase*NH*HD + ts*4;
#pragma unroll 16
            for (int t2 = 0; t2 < TILE; ++t2) {
                float4 vv = *(const float4*)(vb + (size_t)t2*NH*HD);
                float pp = p_lds[s*TILE + t2];
                oacc.x += pp*vv.x; oacc.y += pp*vv.y; oacc.z += pp*vv.z; oacc.w += pp*vv.w;
            }
        } else {
#pragma unroll 8
            for (int t2 = 0; t2 < TILE; ++t2) {
                int tg2 = tbase + t2;
                const float* vrow = ((tg2 >= start && tg2 < T)
                    ? (qkv + (size_t)(b*SS + (tg2-start))*QKV_N + h*HD + 2*HID)
                    : (cache_v + cacheRowBase + (size_t)tg2*NH*HD));
                float4 vv = *(const float4*)(vrow + ts*4);
                float pp = p_lds[s*TILE + t2];
                oacc.x += pp*vv.x; oacc.y += pp*vv.y; oacc.z += pp*vv.z; oacc.w += pp*vv.w;
            }
        }
        asm volatile("s_waitcnt vmcnt(0)" ::: "memory");
        __syncthreads();
        buf ^= 1;
    }

    size_t pbase = ((size_t)(bh*NCHUNK + c) * SS + s) * HD + ts*4;
    *(float4*)(accp + pbase) = oacc;
    if (ts == 0) {
        size_t mb = (size_t)(bh*NCHUNK + c) * 16;
        mlp[mb + s] = m_r;
        mlp[mb + 8 + s] = l_r;
    }
}

// ---------------- combine chunk partials -> attn_out (64 x 4096) ----------------
__global__ __launch_bounds__(256)
void attn_combine(const float* __restrict__ accp, const float* __restrict__ mlp,
                  float* __restrict__ attn_out) {
    const int bh = blockIdx.x;
    const int b = bh >> 5, h = bh & 31;
    const int tid = threadIdx.x;
    const int s = tid >> 5, dg = tid & 31;
    float mC[NCHUNK], lC[NCHUNK];
    float M = -1e30f;
#pragma unroll
    for (int c = 0; c < NCHUNK; ++c) {
        size_t mb = (size_t)(bh*NCHUNK + c) * 16;
        mC[c] = mlp[mb + s];
        lC[c] = mlp[mb + 8 + s];
        M = fmaxf(M, mC[c]);
    }
    float L = 0.f;
    float4 o = make_float4(0.f,0.f,0.f,0.f);
#pragma unroll
    for (int c = 0; c < NCHUNK; ++c) {
        float wgt = __expf(mC[c] - M);
        L += wgt * lC[c];
        float4 a = *(const float4*)(accp + ((size_t)(bh*NCHUNK + c) * SS + s) * HD + dg*4);
        o.x += wgt*a.x; o.y += wgt*a.y; o.z += wgt*a.z; o.w += wgt*a.w;
    }
    float inv = 1.f / L;
    o.x *= inv; o.y *= inv; o.z *= inv; o.w *= inv;
    *(float4*)(attn_out + (size_t)(b*SS + s)*HID + h*HD + dg*4) = o;
}

extern "C" void kernel_launch(void* const* d_in, const int* in_sizes, int n_in,
                              void* d_out, int out_size, void* d_ws, size_t ws_size,
                              hipStream_t stream) {
    const float* tokens  = (const float*)d_in[0];
    const float* cache_k = (const float*)d_in[1];
    const float* cache_v = (const float*)d_in[2];
    const float* gamma   = (const float*)d_in[3];
    const float* beta    = (const float*)d_in[4];
    const float* qkv_w   = (const float*)d_in[5];
    const float* qkv_b   = (const float*)d_in[6];
    const float* proj_w  = (const float*)d_in[7];
    const float* proj_b  = (const float*)d_in[8];
    const int*   d_start = (const int*)d_in[9];
    float* out = (float*)d_out;
    char* ws = (char*)d_ws;

    // layout: x_ln [0,1M) | qkv [1M,4M) | part/accp [4M,16M) | mlp [12M,12.25M)
    // (sequential reuse: part consumed by combine before accp/mlp written;
    //  proj partials use [4M,8M) after attn_combine consumed accp.)
    float* x_ln     = (float*)ws;
    float* qkv      = (float*)(ws + (1u<<20));
    float* part     = (float*)(ws + (4u<<20));
    float* accp     = (float*)(ws + (4u<<20));
    float* mlp      = (float*)(ws + (12u<<20));
    float* attn_out = (float*)(ws + (16u<<20));

    ln_kernel<<<MM, 256, 0, stream>>>(tokens, gamma, beta, x_ln);
    gemm_mfma<<<dim3(QKV_N/64, KSPLIT), 256, 0, stream>>>(x_ln, qkv_w, part, QKV_N, HID);
    combine_bias<<<(MM*QKV_N/4 + 255)/256, 256, 0, stream>>>(part, qkv_b, qkv, QKV_N, MM*QKV_N/4);
    attn_part<<<dim3(BB*NH, NCHUNK), 256, 0, stream>>>(qkv, cache_k, cache_v, d_start, accp, mlp);
    attn_combine<<<BB*NH, 256, 0, stream>>>(accp, mlp, attn_out);
    gemm_mfma<<<dim3(HID/64, KSPLIT), 256, 0, stream>>>(attn_out, proj_w, part, HID, HID);
    combine_bias<<<(MM*HID/4 + 255)/256, 256, 0, stream>>>(part, proj_b, out, HID, MM*HID/4);
}

// Round 7
// 297.976 us; speedup vs baseline: 2.9635x; 1.1580x over previous
//
#include <hip/hip_runtime.h>
#include <math.h>

#define HID 4096
#define NH 32
#define HD 128
#define BB 8
#define SS 8
#define MM 64              // B*S rows
#define MAXT 4096
#define QKV_N (3*HID)      // 12288
#define KSPLIT 4
#define GBK 64             // GEMM K-step
#define ASTR 72            // GEMM LDS row stride (bf16)

// attention geometry
#define ATILE 64                 // K/V rows per staged tile
#define ACHUNK 2048              // t-rows per block
#define NCHUNK (MAXT/ACHUNK)     // 2
#define NTILES (ACHUNK/ATILE)    // 32
#define NPART (NCHUNK*4)         // partials per (b,h): chunks x waves
#define KSTR 136                 // K LDS row stride (bf16, mult of 8)
#define VSTR 88                  // V^T LDS t-stride (bf16, mult of 8, >= 80)
#define PSTR 136                 // P LDS col stride (bf16)

typedef __attribute__((ext_vector_type(8))) __bf16 bf16x8;
typedef __attribute__((ext_vector_type(4))) __bf16 bf16x4;
typedef __attribute__((ext_vector_type(4))) float f32x4;

__device__ __forceinline__ float wred_sum(float v) {
#pragma unroll
    for (int i = 1; i < 64; i <<= 1) v += __shfl_xor(v, i, 64);
    return v;
}

// -------------------- LayerNorm: 64 rows of 4096 --------------------
__global__ __launch_bounds__(256)
void ln_kernel(const float* __restrict__ tokens, const float* __restrict__ gamma,
               const float* __restrict__ beta, float* __restrict__ xout) {
    const int row = blockIdx.x;
    const float* in = tokens + (size_t)row * HID;
    float* out = xout + (size_t)row * HID;
    const int tid = threadIdx.x;
    float s = 0.f, s2 = 0.f;
    float4 vals[4];
#pragma unroll
    for (int i = 0; i < 4; ++i) {
        float4 v = *(const float4*)(in + (size_t)(i*256 + tid)*4);
        vals[i] = v;
        s  += v.x + v.y + v.z + v.w;
        s2 += v.x*v.x + v.y*v.y + v.z*v.z + v.w*v.w;
    }
    s = wred_sum(s); s2 = wred_sum(s2);
    __shared__ float red[8];
    int wid = tid >> 6, lane = tid & 63;
    if (lane == 0) { red[wid] = s; red[4+wid] = s2; }
    __syncthreads();
    s  = red[0]+red[1]+red[2]+red[3];
    s2 = red[4]+red[5]+red[6]+red[7];
    float mean = s * (1.f/HID);
    float var  = s2 * (1.f/HID) - mean*mean;
    float rstd = rsqrtf(var + 1e-5f);
#pragma unroll
    for (int i = 0; i < 4; ++i) {
        int base = (i*256 + tid)*4;
        float4 v = vals[i];
        float4 g  = *(const float4*)(gamma + base);
        float4 bt = *(const float4*)(beta + base);
        float4 o;
        o.x = (v.x - mean)*rstd*g.x + bt.x;
        o.y = (v.y - mean)*rstd*g.y + bt.y;
        o.z = (v.z - mean)*rstd*g.z + bt.z;
        o.w = (v.w - mean)*rstd*g.w + bt.w;
        *(float4*)(out + base) = o;
    }
}

// ---------- split-bf16 MFMA GEMM (unchanged, refcheck'd rounds 5) ----------
__global__ __launch_bounds__(256, 2)
void gemm_mfma(const float* __restrict__ x, const float* __restrict__ w,
               float* __restrict__ part, int N, int K) {
    __shared__ __bf16 a_hi[64*ASTR], a_lo[64*ASTR];
    __shared__ __bf16 b_hi[64*ASTR], b_lo[64*ASTR];
    const int n0 = blockIdx.x * 64;
    const int kc = blockIdx.y;
    const int kLen = K / KSPLIT;
    const int kBeg = kc * kLen;
    const int tid = threadIdx.x;
    const int wv = tid >> 6;
    const int lane = tid & 63;
    const int wm = (wv & 1) * 32;
    const int wn = (wv >> 1) * 32;
    const int sr = tid >> 2;
    const int sk = (tid & 3) * 16;
    const int fm = lane & 15;
    const int fk = (lane >> 4) * 8;

    f32x4 acc[2][2] = {};
    const float* xsrc = x + (size_t)sr * K + kBeg + sk;
    const float* wsrc = w + (size_t)(n0 + sr) * K + kBeg + sk;

    float aRg[16], bRg[16];
#pragma unroll
    for (int q = 0; q < 4; ++q) {
        *(float4*)&aRg[q*4] = *(const float4*)(xsrc + q*4);
        *(float4*)&bRg[q*4] = *(const float4*)(wsrc + q*4);
    }
    const int nsteps = kLen / GBK;
    for (int st = 0; st < nsteps; ++st) {
        __syncthreads();
#pragma unroll
        for (int q = 0; q < 2; ++q) {
            bf16x8 ah, al, bh, bl;
#pragma unroll
            for (int j = 0; j < 8; ++j) {
                float av = aRg[q*8+j];
                __bf16 h = (__bf16)av;
                ah[j] = h;
                al[j] = (__bf16)(av - (float)h);
                float bv = bRg[q*8+j];
                __bf16 g = (__bf16)bv;
                bh[j] = g;
                bl[j] = (__bf16)(bv - (float)g);
            }
            int base = sr*ASTR + sk + q*8;
            *(bf16x8*)&a_hi[base] = ah;
            *(bf16x8*)&a_lo[base] = al;
            *(bf16x8*)&b_hi[base] = bh;
            *(bf16x8*)&b_lo[base] = bl;
        }
        __syncthreads();
        if (st + 1 < nsteps) {
            const float* xn = xsrc + (size_t)(st+1)*GBK;
            const float* wn_ = wsrc + (size_t)(st+1)*GBK;
#pragma unroll
            for (int q = 0; q < 4; ++q) {
                *(float4*)&aRg[q*4] = *(const float4*)(xn + q*4);
                *(float4*)&bRg[q*4] = *(const float4*)(wn_ + q*4);
            }
        }
#pragma unroll
        for (int kh = 0; kh < 2; ++kh) {
            bf16x8 Ah[2], Al[2], Bh[2], Bl[2];
#pragma unroll
            for (int t = 0; t < 2; ++t) {
                int ar = (wm + t*16 + fm)*ASTR + kh*32 + fk;
                Ah[t] = *(const bf16x8*)&a_hi[ar];
                Al[t] = *(const bf16x8*)&a_lo[ar];
                int br = (wn + t*16 + fm)*ASTR + kh*32 + fk;
                Bh[t] = *(const bf16x8*)&b_hi[br];
                Bl[t] = *(const bf16x8*)&b_lo[br];
            }
#pragma unroll
            for (int mt = 0; mt < 2; ++mt)
#pragma unroll
            for (int nt = 0; nt < 2; ++nt) {
                acc[mt][nt] = __builtin_amdgcn_mfma_f32_16x16x32_bf16(Ah[mt], Bh[nt], acc[mt][nt], 0, 0, 0);
                acc[mt][nt] = __builtin_amdgcn_mfma_f32_16x16x32_bf16(Ah[mt], Bl[nt], acc[mt][nt], 0, 0, 0);
                acc[mt][nt] = __builtin_amdgcn_mfma_f32_16x16x32_bf16(Al[mt], Bh[nt], acc[mt][nt], 0, 0, 0);
            }
        }
    }
    float* dst = part + (size_t)kc * MM * N;
#pragma unroll
    for (int mt = 0; mt < 2; ++mt)
#pragma unroll
    for (int nt = 0; nt < 2; ++nt) {
        int m = wm + mt*16 + (lane >> 4)*4;
        int n = n0 + wn + nt*16 + (lane & 15);
#pragma unroll
        for (int r = 0; r < 4; ++r)
            dst[(size_t)(m + r) * N + n] = acc[mt][nt][r];
    }
}

// ---------------- sum KSPLIT partials + bias ----------------
__global__ __launch_bounds__(256)
void combine_bias(const float* __restrict__ part, const float* __restrict__ bias,
                  float* __restrict__ out, int N, int totalv4) {
    int idx = blockIdx.x * 256 + threadIdx.x;
    if (idx >= totalv4) return;
    size_t base = (size_t)idx * 4;
    size_t MN = (size_t)MM * N;
    float4 a = *(const float4*)(part + base);
    float4 b = *(const float4*)(part + MN + base);
    float4 c = *(const float4*)(part + 2*MN + base);
    float4 d = *(const float4*)(part + 3*MN + base);
    int n = (int)(base % (size_t)N);
    float4 bb = *(const float4*)(bias + n);
    float4 o;
    o.x = a.x+b.x+c.x+d.x+bb.x;
    o.y = a.y+b.y+c.y+d.y+bb.y;
    o.z = a.z+b.z+c.z+d.z+bb.z;
    o.w = a.w+b.w+c.w+d.w+bb.w;
    *(float4*)(out + base) = o;
}

// ---------------- MFMA flash attention partial ----------------
// Block = (b,h) x chunk of 2048 t-rows. 4 waves; wave w owns rows
// [w*16, w*16+16) of each 64-row tile, independent online softmax,
// merged in attn_combine (8 partials per (b,h)).
// NaN fix (r6): v_lds pad cols [64,80) are read by wave 3's k-padded PV
// B-frag but never written -> zero once in prologue (0*garbage was NaN).
__global__ __launch_bounds__(256)
void attn_part(const float* __restrict__ qkv, const float* __restrict__ cache_k,
               const float* __restrict__ cache_v, const int* __restrict__ d_start,
               float* __restrict__ accp, float* __restrict__ mlp) {
    __shared__ __bf16 k_lds[ATILE*KSTR];   // 17408 B  [t][d]
    __shared__ __bf16 v_lds[HD*VSTR];      // 22528 B  [d][t] (transposed)
    __shared__ __bf16 p_lds[16*PSTR];      // 4352 B   P^T [s][t-col]
    const int bh = blockIdx.x;
    const int b = bh >> 5, h = bh & 31;
    const int c = blockIdx.y;
    const int tid = threadIdx.x;
    const int w = tid >> 6;
    const int lane = tid & 63;
    const int l15 = lane & 15;
    const int lg  = lane >> 4;          // frag quadrant 0..3
    const int woff = w * 16;            // wave's t-rows within tile
    const int start = d_start[0];
    const int T = start + SS;
    const float scale = 0.08838834764831845f;   // 1/sqrt(128)

    const int d4 = (tid & 31) * 4;      // staging d-chunk
    const int tq = tid >> 5;            // staging row group

    const size_t cacheRowBase = ((size_t)b*MAXT*NH + h) * (size_t)HD;
    const int cbase = c * ACHUNK;

    float4 kreg[8], vreg[8];
#define LOAD_TILE(TB)                                                             \
    {                                                                             \
        _Pragma("unroll")                                                         \
        for (int j = 0; j < 8; ++j) {                                             \
            int tg = (TB) + tq*8 + j;                                             \
            bool fresh = (tg >= start) && (tg < T);                               \
            const float* kp = fresh                                               \
                ? (qkv + (size_t)(b*SS + (tg-start))*QKV_N + h*HD + HID)          \
                : (cache_k + cacheRowBase + (size_t)tg*NH*HD);                    \
            const float* vp = fresh                                               \
                ? (qkv + (size_t)(b*SS + (tg-start))*QKV_N + h*HD + 2*HID)        \
                : (cache_v + cacheRowBase + (size_t)tg*NH*HD);                    \
            kreg[j] = *(const float4*)(kp + d4);                                  \
            vreg[j] = *(const float4*)(vp + d4);                                  \
        }                                                                         \
    }

    // ---- prologue: Q fragments (held in regs for whole kernel) ----
    bf16x8 qf[4];
    if (l15 < SS) {
        const float* qp = qkv + (size_t)(b*SS + l15)*QKV_N + h*HD + lg*8;
#pragma unroll
        for (int ks = 0; ks < 4; ++ks) {
            float4 a = *(const float4*)(qp + ks*32);
            float4 b2 = *(const float4*)(qp + ks*32 + 4);
            bf16x8 q8;
            q8[0]=(__bf16)a.x;  q8[1]=(__bf16)a.y;  q8[2]=(__bf16)a.z;  q8[3]=(__bf16)a.w;
            q8[4]=(__bf16)b2.x; q8[5]=(__bf16)b2.y; q8[6]=(__bf16)b2.z; q8[7]=(__bf16)b2.w;
            qf[ks] = q8;
        }
    } else {
#pragma unroll
        for (int ks = 0; ks < 4; ++ks) qf[ks] = (bf16x8)(__bf16)0.0f;
    }
    // zero P upper k-columns (cols [zw*32+16, zw*32+32), all 16 s rows)
    {
        int zs = tid & 15;
        int zw = (tid >> 4) & 3;
        int zj = tid >> 6;
        *(bf16x4*)&p_lds[zs*PSTR + zw*32 + 16 + zj*4] = (bf16x4)(__bf16)0.0f;
    }
    // zero V^T pad cols [64,80) for all 128 d-rows (read by w=3 PV k-pad)
    {
        int zr = tid & 127;
        int zc = 64 + (tid >> 7) * 8;
        *(bf16x8*)&v_lds[zr*VSTR + zc] = (bf16x8)(__bf16)0.0f;
    }
    LOAD_TILE(cbase);
    __syncthreads();

    float m_r = -1e30f, l_r = 0.f;
    f32x4 oacc[8] = {};

    for (int tile = 0; tile < NTILES; ++tile) {
        const int tbase = cbase + tile*ATILE;
        // ---- convert staged regs -> LDS (K row-major bf16, V transposed) ----
#pragma unroll
        for (int j = 0; j < 8; ++j) {
            bf16x4 kb;
            kb[0]=(__bf16)kreg[j].x; kb[1]=(__bf16)kreg[j].y;
            kb[2]=(__bf16)kreg[j].z; kb[3]=(__bf16)kreg[j].w;
            *(bf16x4*)&k_lds[(tq*8+j)*KSTR + d4] = kb;
        }
#pragma unroll
        for (int i = 0; i < 4; ++i) {
            bf16x8 vt;
#pragma unroll
            for (int j = 0; j < 8; ++j)
                vt[j] = (__bf16)(((const float*)&vreg[j])[i]);
            *(bf16x8*)&v_lds[(d4 + i)*VSTR + tq*8] = vt;
        }
        __syncthreads();   // tile LDS ready
        if (tile + 1 < NTILES) LOAD_TILE(tbase + ATILE);   // lands under compute

        // ---- QK^T: D[t_local][s]; t_local=lg*4+r, s=l15 ----
        f32x4 sacc = {0.f, 0.f, 0.f, 0.f};
#pragma unroll
        for (int ks = 0; ks < 4; ++ks) {
            bf16x8 kf = *(const bf16x8*)&k_lds[(woff + l15)*KSTR + ks*32 + lg*8];
            sacc = __builtin_amdgcn_mfma_f32_16x16x32_bf16(kf, qf[ks], sacc, 0, 0, 0);
        }
        // ---- online softmax (per wave; lane holds s=l15, 4 t rows) ----
        float sc[4]; bool val[4];
#pragma unroll
        for (int r = 0; r < 4; ++r) {
            int tg = tbase + woff + lg*4 + r;
            val[r] = tg < T;
            sc[r] = val[r] ? sacc[r]*scale : -1e30f;
        }
        float tmax = fmaxf(fmaxf(sc[0], sc[1]), fmaxf(sc[2], sc[3]));
        tmax = fmaxf(tmax, __shfl_xor(tmax, 16, 64));
        tmax = fmaxf(tmax, __shfl_xor(tmax, 32, 64));
        float mn = fmaxf(m_r, tmax);
        float al = __expf(m_r - mn);
        float p[4];
#pragma unroll
        for (int r = 0; r < 4; ++r) p[r] = val[r] ? __expf(sc[r] - mn) : 0.f;
        float psum = (p[0]+p[1]) + (p[2]+p[3]);
        psum += __shfl_xor(psum, 16, 64);
        psum += __shfl_xor(psum, 32, 64);
        l_r = l_r * al + psum;
        m_r = mn;
        // write P^T strip: [s=l15][w*32 + lg*4 .. +4]
        bf16x4 pb;
        pb[0]=(__bf16)p[0]; pb[1]=(__bf16)p[1]; pb[2]=(__bf16)p[2]; pb[3]=(__bf16)p[3];
        *(bf16x4*)&p_lds[l15*PSTR + w*32 + lg*4] = pb;
        // rescale oacc rows (s=lg*4+r) by their alpha
        float als[4];
#pragma unroll
        for (int r = 0; r < 4; ++r) als[r] = __shfl(al, lg*4 + r, 64);
#pragma unroll
        for (int dt = 0; dt < 8; ++dt) {
            oacc[dt][0] *= als[0]; oacc[dt][1] *= als[1];
            oacc[dt][2] *= als[2]; oacc[dt][3] *= als[3];
        }
        // ---- PV: A = P^T frag (k=32, upper 16 zero), B = V^T frag ----
        bf16x8 pa = *(const bf16x8*)&p_lds[l15*PSTR + w*32 + lg*8];
#pragma unroll
        for (int dt = 0; dt < 8; ++dt) {
            bf16x8 vb = *(const bf16x8*)&v_lds[(dt*16 + l15)*VSTR + woff + lg*8];
            oacc[dt] = __builtin_amdgcn_mfma_f32_16x16x32_bf16(pa, vb, oacc[dt], 0, 0, 0);
        }
        __syncthreads();   // all readers done before next convert
    }

    // ---- store per-wave partial: acc rows s<8, m, l ----
    const int pidx = (bh*NCHUNK + c)*4 + w;
    float* abase = accp + (size_t)pidx * SS * HD;
#pragma unroll
    for (int r = 0; r < 4; ++r) {
        int s = lg*4 + r;
        if (s < SS) {
#pragma unroll
            for (int dt = 0; dt < 8; ++dt)
                abase[(size_t)s*HD + dt*16 + l15] = oacc[dt][r];
        }
    }
    if (lane < SS) {
        mlp[(size_t)pidx*16 + lane] = m_r;
        mlp[(size_t)pidx*16 + 8 + lane] = l_r;
    }
#undef LOAD_TILE
}

// ---------------- combine NPART partials -> attn_out (64 x 4096) ----------------
__global__ __launch_bounds__(256)
void attn_combine(const float* __restrict__ accp, const float* __restrict__ mlp,
                  float* __restrict__ attn_out) {
    const int bh = blockIdx.x;
    const int b = bh >> 5, h = bh & 31;
    const int tid = threadIdx.x;
    const int s = tid >> 5, dg = tid & 31;
    float mC[NPART], lC[NPART];
    float M = -1e30f;
#pragma unroll
    for (int p = 0; p < NPART; ++p) {
        size_t mb = (size_t)(bh*NPART + p) * 16;
        mC[p] = mlp[mb + s];
        lC[p] = mlp[mb + 8 + s];
        M = fmaxf(M, mC[p]);
    }
    float L = 0.f;
    float4 o = make_float4(0.f,0.f,0.f,0.f);
#pragma unroll
    for (int p = 0; p < NPART; ++p) {
        float wgt = __expf(mC[p] - M);
        L += wgt * lC[p];
        float4 a = *(const float4*)(accp + ((size_t)(bh*NPART + p) * SS + s) * HD + dg*4);
        o.x += wgt*a.x; o.y += wgt*a.y; o.z += wgt*a.z; o.w += wgt*a.w;
    }
    float inv = 1.f / L;
    o.x *= inv; o.y *= inv; o.z *= inv; o.w *= inv;
    *(float4*)(attn_out + (size_t)(b*SS + s)*HID + h*HD + dg*4) = o;
}

extern "C" void kernel_launch(void* const* d_in, const int* in_sizes, int n_in,
                              void* d_out, int out_size, void* d_ws, size_t ws_size,
                              hipStream_t stream) {
    const float* tokens  = (const float*)d_in[0];
    const float* cache_k = (const float*)d_in[1];
    const float* cache_v = (const float*)d_in[2];
    const float* gamma   = (const float*)d_in[3];
    const float* beta    = (const float*)d_in[4];
    const float* qkv_w   = (const float*)d_in[5];
    const float* qkv_b   = (const float*)d_in[6];
    const float* proj_w  = (const float*)d_in[7];
    const float* proj_b  = (const float*)d_in[8];
    const int*   d_start = (const int*)d_in[9];
    float* out = (float*)d_out;
    char* ws = (char*)d_ws;

    // layout: x_ln [0,1M) | qkv [1M,4M) | part/accp [4M,12M) | mlp [12M,12.25M)
    // sequential reuse: qkv-gemm partials consumed before accp written;
    // proj partials [4M,8M) written after attn_combine consumed accp.
    float* x_ln     = (float*)ws;
    float* qkv      = (float*)(ws + (1u<<20));
    float* part     = (float*)(ws + (4u<<20));
    float* accp     = (float*)(ws + (4u<<20));
    float* mlp      = (float*)(ws + (12u<<20));
    float* attn_out = (float*)(ws + (16u<<20));

    ln_kernel<<<MM, 256, 0, stream>>>(tokens, gamma, beta, x_ln);
    gemm_mfma<<<dim3(QKV_N/64, KSPLIT), 256, 0, stream>>>(x_ln, qkv_w, part, QKV_N, HID);
    combine_bias<<<(MM*QKV_N/4 + 255)/256, 256, 0, stream>>>(part, qkv_b, qkv, QKV_N, MM*QKV_N/4);
    attn_part<<<dim3(BB*NH, NCHUNK), 256, 0, stream>>>(qkv, cache_k, cache_v, d_start, accp, mlp);
    attn_combine<<<BB*NH, 256, 0, stream>>>(accp, mlp, attn_out);
    gemm_mfma<<<dim3(HID/64, KSPLIT), 256, 0, stream>>>(attn_out, proj_w, part, HID, HID);
    combine_bias<<<(MM*HID/4 + 255)/256, 256, 0, stream>>>(part, proj_b, out, HID, MM*HID/4);
}

// Round 8
// 289.254 us; speedup vs baseline: 3.0528x; 1.0302x over previous
//
#include <hip/hip_runtime.h>
#include <math.h>

#define HID 4096
#define NH 32
#define HD 128
#define BB 8
#define SS 8
#define MM 64              // B*S rows
#define MAXT 4096
#define QKV_N (3*HID)      // 12288
#define GBK 64             // GEMM K-step
#define ASTR 72            // GEMM LDS row stride (bf16)

// attention geometry
#define ATILE 64                 // K/V rows per staged tile
#define ACHUNK 2048              // t-rows per block
#define NCHUNK (MAXT/ACHUNK)     // 2
#define NTILES (ACHUNK/ATILE)    // 32
#define NPART (NCHUNK*4)         // partials per (b,h): chunks x waves
#define KSTR 136                 // K LDS row stride (bf16, mult of 8)
#define VSTR 88                  // V^T LDS t-stride (bf16; 88 -> rows spread 8 bank-quads)
#define PSTR 136                 // P LDS col stride (bf16)

typedef __attribute__((ext_vector_type(8))) __bf16 bf16x8;
typedef __attribute__((ext_vector_type(4))) __bf16 bf16x4;
typedef __attribute__((ext_vector_type(4))) float f32x4;

__device__ __forceinline__ float wred_sum(float v) {
#pragma unroll
    for (int i = 1; i < 64; i <<= 1) v += __shfl_xor(v, i, 64);
    return v;
}

// -------------------- LayerNorm: 64 rows of 4096 --------------------
__global__ __launch_bounds__(256)
void ln_kernel(const float* __restrict__ tokens, const float* __restrict__ gamma,
               const float* __restrict__ beta, float* __restrict__ xout) {
    const int row = blockIdx.x;
    const float* in = tokens + (size_t)row * HID;
    float* out = xout + (size_t)row * HID;
    const int tid = threadIdx.x;
    float s = 0.f, s2 = 0.f;
    float4 vals[4];
#pragma unroll
    for (int i = 0; i < 4; ++i) {
        float4 v = *(const float4*)(in + (size_t)(i*256 + tid)*4);
        vals[i] = v;
        s  += v.x + v.y + v.z + v.w;
        s2 += v.x*v.x + v.y*v.y + v.z*v.z + v.w*v.w;
    }
    s = wred_sum(s); s2 = wred_sum(s2);
    __shared__ float red[8];
    int wid = tid >> 6, lane = tid & 63;
    if (lane == 0) { red[wid] = s; red[4+wid] = s2; }
    __syncthreads();
    s  = red[0]+red[1]+red[2]+red[3];
    s2 = red[4]+red[5]+red[6]+red[7];
    float mean = s * (1.f/HID);
    float var  = s2 * (1.f/HID) - mean*mean;
    float rstd = rsqrtf(var + 1e-5f);
#pragma unroll
    for (int i = 0; i < 4; ++i) {
        int base = (i*256 + tid)*4;
        float4 v = vals[i];
        float4 g  = *(const float4*)(gamma + base);
        float4 bt = *(const float4*)(beta + base);
        float4 o;
        o.x = (v.x - mean)*rstd*g.x + bt.x;
        o.y = (v.y - mean)*rstd*g.y + bt.y;
        o.z = (v.z - mean)*rstd*g.z + bt.z;
        o.w = (v.w - mean)*rstd*g.w + bt.w;
        *(float4*)(out + base) = o;
    }
}

// ---------- split-bf16 MFMA GEMM: part[kc][m][n] = sum_k x[m,k]*w[n,k] ----------
// kparts k-range partials; (256,3): 3 blocks/CU resident (was 2 -> 1.5 gens for qkv,
// 1 block/CU for proj). Live VGPR ~110 < 170 cap -> no spill.
__global__ __launch_bounds__(256, 3)
void gemm_mfma(const float* __restrict__ x, const float* __restrict__ w,
               float* __restrict__ part, int N, int K, int kparts) {
    __shared__ __bf16 a_hi[64*ASTR], a_lo[64*ASTR];
    __shared__ __bf16 b_hi[64*ASTR], b_lo[64*ASTR];
    const int n0 = blockIdx.x * 64;
    const int kc = blockIdx.y;
    const int kLen = K / kparts;
    const int kBeg = kc * kLen;
    const int tid = threadIdx.x;
    const int wv = tid >> 6;
    const int lane = tid & 63;
    const int wm = (wv & 1) * 32;
    const int wn = (wv >> 1) * 32;
    const int sr = tid >> 2;
    const int sk = (tid & 3) * 16;
    const int fm = lane & 15;
    const int fk = (lane >> 4) * 8;

    f32x4 acc[2][2] = {};
    const float* xsrc = x + (size_t)sr * K + kBeg + sk;
    const float* wsrc = w + (size_t)(n0 + sr) * K + kBeg + sk;

    float aRg[16], bRg[16];
#pragma unroll
    for (int q = 0; q < 4; ++q) {
        *(float4*)&aRg[q*4] = *(const float4*)(xsrc + q*4);
        *(float4*)&bRg[q*4] = *(const float4*)(wsrc + q*4);
    }
    const int nsteps = kLen / GBK;
    for (int st = 0; st < nsteps; ++st) {
        __syncthreads();
#pragma unroll
        for (int q = 0; q < 2; ++q) {
            bf16x8 ah, al, bh, bl;
#pragma unroll
            for (int j = 0; j < 8; ++j) {
                float av = aRg[q*8+j];
                __bf16 h = (__bf16)av;
                ah[j] = h;
                al[j] = (__bf16)(av - (float)h);
                float bv = bRg[q*8+j];
                __bf16 g = (__bf16)bv;
                bh[j] = g;
                bl[j] = (__bf16)(bv - (float)g);
            }
            int base = sr*ASTR + sk + q*8;
            *(bf16x8*)&a_hi[base] = ah;
            *(bf16x8*)&a_lo[base] = al;
            *(bf16x8*)&b_hi[base] = bh;
            *(bf16x8*)&b_lo[base] = bl;
        }
        __syncthreads();
        if (st + 1 < nsteps) {   // T14: issue next loads; they land during MFMA
            const float* xn = xsrc + (size_t)(st+1)*GBK;
            const float* wn_ = wsrc + (size_t)(st+1)*GBK;
#pragma unroll
            for (int q = 0; q < 4; ++q) {
                *(float4*)&aRg[q*4] = *(const float4*)(xn + q*4);
                *(float4*)&bRg[q*4] = *(const float4*)(wn_ + q*4);
            }
        }
#pragma unroll
        for (int kh = 0; kh < 2; ++kh) {
            bf16x8 Ah[2], Al[2], Bh[2], Bl[2];
#pragma unroll
            for (int t = 0; t < 2; ++t) {
                int ar = (wm + t*16 + fm)*ASTR + kh*32 + fk;
                Ah[t] = *(const bf16x8*)&a_hi[ar];
                Al[t] = *(const bf16x8*)&a_lo[ar];
                int br = (wn + t*16 + fm)*ASTR + kh*32 + fk;
                Bh[t] = *(const bf16x8*)&b_hi[br];
                Bl[t] = *(const bf16x8*)&b_lo[br];
            }
#pragma unroll
            for (int mt = 0; mt < 2; ++mt)
#pragma unroll
            for (int nt = 0; nt < 2; ++nt) {
                acc[mt][nt] = __builtin_amdgcn_mfma_f32_16x16x32_bf16(Ah[mt], Bh[nt], acc[mt][nt], 0, 0, 0);
                acc[mt][nt] = __builtin_amdgcn_mfma_f32_16x16x32_bf16(Ah[mt], Bl[nt], acc[mt][nt], 0, 0, 0);
                acc[mt][nt] = __builtin_amdgcn_mfma_f32_16x16x32_bf16(Al[mt], Bh[nt], acc[mt][nt], 0, 0, 0);
            }
        }
    }
    float* dst = part + (size_t)kc * MM * N;
#pragma unroll
    for (int mt = 0; mt < 2; ++mt)
#pragma unroll
    for (int nt = 0; nt < 2; ++nt) {
        int m = wm + mt*16 + (lane >> 4)*4;
        int n = n0 + wn + nt*16 + (lane & 15);
#pragma unroll
        for (int r = 0; r < 4; ++r)
            dst[(size_t)(m + r) * N + n] = acc[mt][nt][r];
    }
}

// ---------------- sum nparts partials + bias ----------------
__global__ __launch_bounds__(256)
void combine_bias(const float* __restrict__ part, const float* __restrict__ bias,
                  float* __restrict__ out, int N, int totalv4, int nparts) {
    int idx = blockIdx.x * 256 + threadIdx.x;
    if (idx >= totalv4) return;
    size_t base = (size_t)idx * 4;
    size_t MN = (size_t)MM * N;
    float4 o = make_float4(0.f,0.f,0.f,0.f);
    for (int p = 0; p < nparts; ++p) {
        float4 a = *(const float4*)(part + (size_t)p * MN + base);
        o.x += a.x; o.y += a.y; o.z += a.z; o.w += a.w;
    }
    int n = (int)(base % (size_t)N);
    float4 bb = *(const float4*)(bias + n);
    o.x += bb.x; o.y += bb.y; o.z += bb.z; o.w += bb.w;
    *(float4*)(out + base) = o;
}

// ---------------- MFMA flash attention partial (unchanged from r7) ----------------
__global__ __launch_bounds__(256)
void attn_part(const float* __restrict__ qkv, const float* __restrict__ cache_k,
               const float* __restrict__ cache_v, const int* __restrict__ d_start,
               float* __restrict__ accp, float* __restrict__ mlp) {
    __shared__ __bf16 k_lds[ATILE*KSTR];   // 17408 B  [t][d]
    __shared__ __bf16 v_lds[HD*VSTR];      // 22528 B  [d][t] (transposed)
    __shared__ __bf16 p_lds[16*PSTR];      // 4352 B   P^T [s][t-col]
    const int bh = blockIdx.x;
    const int b = bh >> 5, h = bh & 31;
    const int c = blockIdx.y;
    const int tid = threadIdx.x;
    const int w = tid >> 6;
    const int lane = tid & 63;
    const int l15 = lane & 15;
    const int lg  = lane >> 4;          // frag quadrant 0..3
    const int woff = w * 16;            // wave's t-rows within tile
    const int start = d_start[0];
    const int T = start + SS;
    const float scale = 0.08838834764831845f;   // 1/sqrt(128)

    const int d4 = (tid & 31) * 4;      // staging d-chunk
    const int tq = tid >> 5;            // staging row group

    const size_t cacheRowBase = ((size_t)b*MAXT*NH + h) * (size_t)HD;
    const int cbase = c * ACHUNK;

    float4 kreg[8], vreg[8];
#define LOAD_TILE(TB)                                                             \
    {                                                                             \
        _Pragma("unroll")                                                         \
        for (int j = 0; j < 8; ++j) {                                             \
            int tg = (TB) + tq*8 + j;                                             \
            bool fresh = (tg >= start) && (tg < T);                               \
            const float* kp = fresh                                               \
                ? (qkv + (size_t)(b*SS + (tg-start))*QKV_N + h*HD + HID)          \
                : (cache_k + cacheRowBase + (size_t)tg*NH*HD);                    \
            const float* vp = fresh                                               \
                ? (qkv + (size_t)(b*SS + (tg-start))*QKV_N + h*HD + 2*HID)        \
                : (cache_v + cacheRowBase + (size_t)tg*NH*HD);                    \
            kreg[j] = *(const float4*)(kp + d4);                                  \
            vreg[j] = *(const float4*)(vp + d4);                                  \
        }                                                                         \
    }

    // ---- prologue: Q fragments (held in regs for whole kernel) ----
    bf16x8 qf[4];
    if (l15 < SS) {
        const float* qp = qkv + (size_t)(b*SS + l15)*QKV_N + h*HD + lg*8;
#pragma unroll
        for (int ks = 0; ks < 4; ++ks) {
            float4 a = *(const float4*)(qp + ks*32);
            float4 b2 = *(const float4*)(qp + ks*32 + 4);
            bf16x8 q8;
            q8[0]=(__bf16)a.x;  q8[1]=(__bf16)a.y;  q8[2]=(__bf16)a.z;  q8[3]=(__bf16)a.w;
            q8[4]=(__bf16)b2.x; q8[5]=(__bf16)b2.y; q8[6]=(__bf16)b2.z; q8[7]=(__bf16)b2.w;
            qf[ks] = q8;
        }
    } else {
#pragma unroll
        for (int ks = 0; ks < 4; ++ks) qf[ks] = (bf16x8)(__bf16)0.0f;
    }
    // zero P upper k-columns (cols [zw*32+16, zw*32+32), all 16 s rows)
    {
        int zs = tid & 15;
        int zw = (tid >> 4) & 3;
        int zj = tid >> 6;
        *(bf16x4*)&p_lds[zs*PSTR + zw*32 + 16 + zj*4] = (bf16x4)(__bf16)0.0f;
    }
    // zero V^T pad cols [64,80) for all 128 d-rows (read by w=3 PV k-pad)
    {
        int zr = tid & 127;
        int zc = 64 + (tid >> 7) * 8;
        *(bf16x8*)&v_lds[zr*VSTR + zc] = (bf16x8)(__bf16)0.0f;
    }
    LOAD_TILE(cbase);
    __syncthreads();

    float m_r = -1e30f, l_r = 0.f;
    f32x4 oacc[8] = {};

    for (int tile = 0; tile < NTILES; ++tile) {
        const int tbase = cbase + tile*ATILE;
        // ---- convert staged regs -> LDS (K row-major bf16, V transposed) ----
#pragma unroll
        for (int j = 0; j < 8; ++j) {
            bf16x4 kb;
            kb[0]=(__bf16)kreg[j].x; kb[1]=(__bf16)kreg[j].y;
            kb[2]=(__bf16)kreg[j].z; kb[3]=(__bf16)kreg[j].w;
            *(bf16x4*)&k_lds[(tq*8+j)*KSTR + d4] = kb;
        }
#pragma unroll
        for (int i = 0; i < 4; ++i) {
            bf16x8 vt;
#pragma unroll
            for (int j = 0; j < 8; ++j)
                vt[j] = (__bf16)(((const float*)&vreg[j])[i]);
            *(bf16x8*)&v_lds[(d4 + i)*VSTR + tq*8] = vt;
        }
        __syncthreads();   // tile LDS ready
        if (tile + 1 < NTILES) LOAD_TILE(tbase + ATILE);   // lands under compute

        // ---- QK^T: D[t_local][s]; t_local=lg*4+r, s=l15 ----
        f32x4 sacc = {0.f, 0.f, 0.f, 0.f};
#pragma unroll
        for (int ks = 0; ks < 4; ++ks) {
            bf16x8 kf = *(const bf16x8*)&k_lds[(woff + l15)*KSTR + ks*32 + lg*8];
            sacc = __builtin_amdgcn_mfma_f32_16x16x32_bf16(kf, qf[ks], sacc, 0, 0, 0);
        }
        // ---- online softmax (per wave; lane holds s=l15, 4 t rows) ----
        float sc[4]; bool val[4];
#pragma unroll
        for (int r = 0; r < 4; ++r) {
            int tg = tbase + woff + lg*4 + r;
            val[r] = tg < T;
            sc[r] = val[r] ? sacc[r]*scale : -1e30f;
        }
        float tmax = fmaxf(fmaxf(sc[0], sc[1]), fmaxf(sc[2], sc[3]));
        tmax = fmaxf(tmax, __shfl_xor(tmax, 16, 64));
        tmax = fmaxf(tmax, __shfl_xor(tmax, 32, 64));
        float mn = fmaxf(m_r, tmax);
        float al = __expf(m_r - mn);
        float p[4];
#pragma unroll
        for (int r = 0; r < 4; ++r) p[r] = val[r] ? __expf(sc[r] - mn) : 0.f;
        float psum = (p[0]+p[1]) + (p[2]+p[3]);
        psum += __shfl_xor(psum, 16, 64);
        psum += __shfl_xor(psum, 32, 64);
        l_r = l_r * al + psum;
        m_r = mn;
        // write P^T strip: [s=l15][w*32 + lg*4 .. +4]
        bf16x4 pb;
        pb[0]=(__bf16)p[0]; pb[1]=(__bf16)p[1]; pb[2]=(__bf16)p[2]; pb[3]=(__bf16)p[3];
        *(bf16x4*)&p_lds[l15*PSTR + w*32 + lg*4] = pb;
        // rescale oacc rows (s=lg*4+r) by their alpha
        float als[4];
#pragma unroll
        for (int r = 0; r < 4; ++r) als[r] = __shfl(al, lg*4 + r, 64);
#pragma unroll
        for (int dt = 0; dt < 8; ++dt) {
            oacc[dt][0] *= als[0]; oacc[dt][1] *= als[1];
            oacc[dt][2] *= als[2]; oacc[dt][3] *= als[3];
        }
        // ---- PV: A = P^T frag (k=32, upper 16 zero), B = V^T frag ----
        bf16x8 pa = *(const bf16x8*)&p_lds[l15*PSTR + w*32 + lg*8];
#pragma unroll
        for (int dt = 0; dt < 8; ++dt) {
            bf16x8 vb = *(const bf16x8*)&v_lds[(dt*16 + l15)*VSTR + woff + lg*8];
            oacc[dt] = __builtin_amdgcn_mfma_f32_16x16x32_bf16(pa, vb, oacc[dt], 0, 0, 0);
        }
        __syncthreads();   // all readers done before next convert
    }

    // ---- store per-wave partial: acc rows s<8, m, l ----
    const int pidx = (bh*NCHUNK + c)*4 + w;
    float* abase = accp + (size_t)pidx * SS * HD;
#pragma unroll
    for (int r = 0; r < 4; ++r) {
        int s = lg*4 + r;
        if (s < SS) {
#pragma unroll
            for (int dt = 0; dt < 8; ++dt)
                abase[(size_t)s*HD + dt*16 + l15] = oacc[dt][r];
        }
    }
    if (lane < SS) {
        mlp[(size_t)pidx*16 + lane] = m_r;
        mlp[(size_t)pidx*16 + 8 + lane] = l_r;
    }
#undef LOAD_TILE
}

// ---------------- combine NPART partials -> attn_out (64 x 4096) ----------------
__global__ __launch_bounds__(256)
void attn_combine(const float* __restrict__ accp, const float* __restrict__ mlp,
                  float* __restrict__ attn_out) {
    const int bh = blockIdx.x;
    const int b = bh >> 5, h = bh & 31;
    const int tid = threadIdx.x;
    const int s = tid >> 5, dg = tid & 31;
    float mC[NPART], lC[NPART];
    float M = -1e30f;
#pragma unroll
    for (int p = 0; p < NPART; ++p) {
        size_t mb = (size_t)(bh*NPART + p) * 16;
        mC[p] = mlp[mb + s];
        lC[p] = mlp[mb + 8 + s];
        M = fmaxf(M, mC[p]);
    }
    float L = 0.f;
    float4 o = make_float4(0.f,0.f,0.f,0.f);
#pragma unroll
    for (int p = 0; p < NPART; ++p) {
        float wgt = __expf(mC[p] - M);
        L += wgt * lC[p];
        float4 a = *(const float4*)(accp + ((size_t)(bh*NPART + p) * SS + s) * HD + dg*4);
        o.x += wgt*a.x; o.y += wgt*a.y; o.z += wgt*a.z; o.w += wgt*a.w;
    }
    float inv = 1.f / L;
    o.x *= inv; o.y *= inv; o.z *= inv; o.w *= inv;
    *(float4*)(attn_out + (size_t)(b*SS + s)*HID + h*HD + dg*4) = o;
}

extern "C" void kernel_launch(void* const* d_in, const int* in_sizes, int n_in,
                              void* d_out, int out_size, void* d_ws, size_t ws_size,
                              hipStream_t stream) {
    const float* tokens  = (const float*)d_in[0];
    const float* cache_k = (const float*)d_in[1];
    const float* cache_v = (const float*)d_in[2];
    const float* gamma   = (const float*)d_in[3];
    const float* beta    = (const float*)d_in[4];
    const float* qkv_w   = (const float*)d_in[5];
    const float* qkv_b   = (const float*)d_in[6];
    const float* proj_w  = (const float*)d_in[7];
    const float* proj_b  = (const float*)d_in[8];
    const int*   d_start = (const int*)d_in[9];
    float* out = (float*)d_out;
    char* ws = (char*)d_ws;

    // layout: x_ln [0,1M) | qkv [1M,4M) | part/accp [4M,12M) | mlp [12M,12.25M)
    // sequential reuse: qkv-gemm partials consumed before accp written;
    // proj partials (8 x 1MB = 8MB) written after attn_combine consumed accp.
    float* x_ln     = (float*)ws;
    float* qkv      = (float*)(ws + (1u<<20));
    float* part     = (float*)(ws + (4u<<20));
    float* accp     = (float*)(ws + (4u<<20));
    float* mlp      = (float*)(ws + (12u<<20));
    float* attn_out = (float*)(ws + (16u<<20));

    ln_kernel<<<MM, 256, 0, stream>>>(tokens, gamma, beta, x_ln);
    gemm_mfma<<<dim3(QKV_N/64, 4), 256, 0, stream>>>(x_ln, qkv_w, part, QKV_N, HID, 4);
    combine_bias<<<(MM*QKV_N/4 + 255)/256, 256, 0, stream>>>(part, qkv_b, qkv, QKV_N, MM*QKV_N/4, 4);
    attn_part<<<dim3(BB*NH, NCHUNK), 256, 0, stream>>>(qkv, cache_k, cache_v, d_start, accp, mlp);
    attn_combine<<<BB*NH, 256, 0, stream>>>(accp, mlp, attn_out);
    gemm_mfma<<<dim3(HID/64, 8), 256, 0, stream>>>(attn_out, proj_w, part, HID, HID, 8);
    combine_bias<<<(MM*HID/4 + 255)/256, 256, 0, stream>>>(part, proj_b, out, HID, MM*HID/4, 8);
}